// Round 10
// baseline (186.123 us; speedup 1.0000x reference)
//
#include <hip/hip_runtime.h>
#include <hip/hip_bf16.h>
#include <stdint.h>

typedef __bf16 bf16x8 __attribute__((ext_vector_type(8)));
typedef __bf16 bf16x4 __attribute__((ext_vector_type(4)));
typedef float  f32x4  __attribute__((ext_vector_type(4)));

#define MFMA16(a, b, c) __builtin_amdgcn_mfma_f32_16x16x32_bf16(a, b, c, 0, 0, 0)

#if __has_builtin(__builtin_amdgcn_exp2f)
#define EXP2(x) __builtin_amdgcn_exp2f(x)
#else
#define EXP2(x) exp2f(x)
#endif

// async 16B global->LDS (dest = wave-uniform base + lane*16)
__device__ __forceinline__ void ld16(void* lds, const void* g) {
    __builtin_amdgcn_global_load_lds(
        (const __attribute__((address_space(1))) void*)(uintptr_t)g,
        (__attribute__((address_space(3))) void*)(uint32_t)(uintptr_t)lds,
        16, 0, 0);
}

// ---------------- fused prep: weight transpose x4 + x f32->bf16 ----------------
__global__ __launch_bounds__(1024) void prep_kernel(const float* __restrict__ x,
                                                    const float* __restrict__ W0,
                                                    const float* __restrict__ W1,
                                                    const float* __restrict__ W2,
                                                    const float* __restrict__ W3,
                                                    __bf16* __restrict__ wdst,
                                                    __bf16* __restrict__ xdst) {
    __shared__ __bf16 t[32][33];
    const int z = blockIdx.z;
    const int tx = threadIdx.x, ty = threadIdx.y;
    if (z == 4) {
        int blin = blockIdx.y * 32 + blockIdx.x;
        int i = (blin * 1024 + ty * 32 + tx) * 4;
        float4 v = *(const float4*)(x + i);
        xdst[i]     = (__bf16)v.x;
        xdst[i + 1] = (__bf16)v.y;
        xdst[i + 2] = (__bf16)v.z;
        xdst[i + 3] = (__bf16)v.w;
        return;
    }
    const float* W = (z == 0) ? W0 : (z == 1) ? W1 : (z == 2) ? W2 : W3;
    __bf16* D = wdst + (size_t)z * 1048576;
    t[ty][tx] = (__bf16)W[(size_t)(blockIdx.y * 32 + ty) * 1024 + blockIdx.x * 32 + tx];
    __syncthreads();
    D[(size_t)(blockIdx.x * 32 + ty) * 1024 + blockIdx.y * 32 + tx] = t[tx][ty];
}

// ---------------- shared GEMM mainloop: C[128x128] += A[128xK] * BT[128xK]^T ----
// Round 10: A/B-row-INTERLEAVED LDS tile. Hardware model (validated r6 vs r7):
// ds_read_b128 resolves banks per 8-lane group (8 x 16B = all 32 banks), so
// conflict-free needs the 8 slots of a 128B row XOR-spanned by row&7 -- r6
// proved it (conflicts 3.15M -> 0) but paid 2x LDS via BK=64. Here: combined
// row r (128B) = A-row r (slots s with s^(r&7)<4) + B-row r (slots >=4).
// Same 16 KB, same BK=32, same occupancy. Staging dest stays linear
// (lane*16 = (lane>>3)*128 + (lane&7)*16); per-lane SOURCE selects A or B by
// v = (lane&7)^(lane>>3) (rule 21: swizzle via pre-permuted global source).
// Reads: af slot = quad^(l16&7), bf slot = (quad+4)^(l16&7): each 8-lane
// group (constant quad, full l16&7 span) covers all 8 slots -> 32 banks.
__device__ __forceinline__ void gemm_mainloop(const __bf16* __restrict__ A,
                                              const __bf16* __restrict__ BT,
                                              int K, __bf16* Cs,
                                              f32x4 acc[4][4]) {
    const int tid  = threadIdx.x;
    const int lane = tid & 63;
    const int wid  = tid >> 6;
    const int quad = lane >> 4;
    const int l16  = lane & 15;
    const int wm   = wid >> 1;
    const int wn   = wid & 1;
    const int l8   = l16 & 7;

    // staging constants: lane covers slot (lane&7) of row (base + lane>>3)
    const int lr = lane >> 3;                 // row-in-8-group
    const int v  = (lane & 7) ^ lr;           // source chunk id (involution)
    const __bf16* sb = (v < 4) ? A : BT;      // per-lane A/B select
    const int co = (v & 3) * 8;               // source column offset (elems)

    for (int k0 = 0; k0 < K; k0 += 32) {
        // 128 rows x 128B; wave wid stages rows [wid*32, wid*32+32)
#pragma unroll
        for (int i = 0; i < 4; i++) {
            const int r0 = wid * 32 + i * 8;
            ld16((char*)Cs + r0 * 128 + lane * 16,
                 sb + (size_t)(r0 + lr) * K + k0 + co);
        }
        __syncthreads();
        bf16x8 af[4], bf[4];
#pragma unroll
        for (int mt = 0; mt < 4; mt++)
            af[mt] = *(const bf16x8*)(Cs + (wm * 64 + mt * 16 + l16) * 64 +
                                      ((quad ^ l8) << 3));
#pragma unroll
        for (int nt = 0; nt < 4; nt++)
            bf[nt] = *(const bf16x8*)(Cs + (wn * 64 + nt * 16 + l16) * 64 +
                                      (((quad + 4) ^ l8) << 3));
#pragma unroll
        for (int mt = 0; mt < 4; mt++)
#pragma unroll
            for (int nt = 0; nt < 4; nt++)
                acc[mt][nt] = MFMA16(af[mt], bf[nt], acc[mt][nt]);
        __syncthreads();
    }
}

// ---- proj mainloop: C[64x128] += A[64xK] * BT[128xK]^T (2 blocks/CU, r9) ------
__device__ __forceinline__ void mainloop64(const __bf16* __restrict__ A,
                                           const __bf16* __restrict__ BT,
                                           int K, __bf16* As, __bf16* Bs,
                                           f32x4 acc[2][4]) {
    const int tid  = threadIdx.x;
    const int lane = tid & 63;
    const int quad = lane >> 4;
    const int l16  = lane & 15;
    const int wid  = tid >> 6;
    const int wm   = wid >> 1;          // 0..1: 32-row half
    const int wn   = wid & 1;           // 0..1: 64-col half
    const int srow = tid >> 2;          // 0..63
    const int scol = (tid & 3) * 8;

    for (int k0 = 0; k0 < K; k0 += 32) {
        ld16(As + tid * 8,        A  + (size_t)srow        * K + k0 + scol);
        ld16(Bs + tid * 8,        BT + (size_t)srow        * K + k0 + scol);
        ld16(Bs + 2048 + tid * 8, BT + (size_t)(srow + 64) * K + k0 + scol);
        __syncthreads();
        bf16x8 af[2], bf[4];
#pragma unroll
        for (int mt = 0; mt < 2; mt++)
            af[mt] = *(const bf16x8*)(As + (wm * 32 + mt * 16 + l16) * 32 + quad * 8);
#pragma unroll
        for (int nt = 0; nt < 4; nt++)
            bf[nt] = *(const bf16x8*)(Bs + (wn * 64 + nt * 16 + l16) * 32 + quad * 8);
#pragma unroll
        for (int mt = 0; mt < 2; mt++)
#pragma unroll
            for (int nt = 0; nt < 4; nt++)
                acc[mt][nt] = MFMA16(af[mt], bf[nt], acc[mt][nt]);
        __syncthreads();
    }
}

// ---------------- QKV projection: X @ W{q,k,v} + b ------------------------------
// XCD super-tiling (round 3, verified: FETCH 68.7 -> 20.5 MB).
// z=0 -> Q [B,H,T,HD] PRE-SCALED by (1/8)*log2(e), z=1 -> K, z=2 -> V^T
__global__ __launch_bounds__(256) void qkv_gemm(const __bf16* __restrict__ X,
                                                const __bf16* __restrict__ WTb,
                                                const float* __restrict__ b0,
                                                const float* __restrict__ b1,
                                                const float* __restrict__ b2,
                                                __bf16* __restrict__ qk,
                                                __bf16* __restrict__ vt) {
    __shared__ __attribute__((aligned(16))) __bf16 Cs[8192];   // interleaved A|B
    const int o  = blockIdx.x;
    const int g  = o & 7, r = o >> 3;
    const int mB = ((g >> 1) << 3) + (r & 7);     // m-tile 0..31
    const int nz = (g & 1) * 12 + (r >> 3);       // 0..23
    const int z  = nz >> 3;                       // 0..2
    const int n  = nz & 7;                        // 0..7
    const __bf16* BT   = WTb + (size_t)z * 1048576;
    const float* bias  = (z == 0) ? b0 : (z == 1) ? b1 : b2;
    const int m0 = mB * 128, n0 = n * 128;
    f32x4 acc[4][4];
    const f32x4 zz = {0.f, 0.f, 0.f, 0.f};
#pragma unroll
    for (int i = 0; i < 4; i++)
#pragma unroll
        for (int j = 0; j < 4; j++) acc[i][j] = zz;
    gemm_mainloop(X + (size_t)m0 * 1024, BT + (size_t)n0 * 1024, 1024, Cs, acc);

    const int lane = threadIdx.x & 63, wid = threadIdx.x >> 6;
    const int quad = lane >> 4, l16 = lane & 15, wm = wid >> 1, wn = wid & 1;
    if (z == 2) {
        // V^T epilogue: vt[((b*16+h)*64+hd)*2048 + t], 4 consecutive t packed
#pragma unroll
        for (int nt = 0; nt < 4; nt++) {
            int col = n0 + wn * 64 + nt * 16 + l16;
            float bv = bias[col];
            int h = col >> 6, hd = col & 63;
#pragma unroll
            for (int mt = 0; mt < 4; mt++) {
                int m = m0 + wm * 64 + mt * 16 + quad * 4;
                int b = m >> 11, tt = m & 2047;
                bf16x4 pk;
                pk.x = (__bf16)(acc[mt][nt].x + bv);
                pk.y = (__bf16)(acc[mt][nt].y + bv);
                pk.z = (__bf16)(acc[mt][nt].z + bv);
                pk.w = (__bf16)(acc[mt][nt].w + bv);
                *(bf16x4*)(vt + ((size_t)((b * 16 + h) * 64 + hd)) * 2048 + tt) = pk;
            }
        }
    } else {
        // softmax scale (1/sqrt(64))*log2(e) folded into Q here (z==0)
        const float sq = (z == 0) ? 0.18033688011112042f : 1.0f;
        __bf16* dst = qk + (size_t)z * 4194304;
#pragma unroll
        for (int nt = 0; nt < 4; nt++) {
            int col = n0 + wn * 64 + nt * 16 + l16;
            float bv = bias[col];
            int h = col >> 6, hd = col & 63;
#pragma unroll
            for (int mt = 0; mt < 4; mt++) {
#pragma unroll
                for (int r4 = 0; r4 < 4; r4++) {
                    int m = m0 + wm * 64 + mt * 16 + quad * 4 + r4;
                    int b = m >> 11, tt = m & 2047;
                    float v = (acc[mt][nt][r4] + bv) * sq;
                    dst[((size_t)((b * 16 + h) * 2048 + tt)) * 64 + hd] = (__bf16)v;
                }
            }
        }
    }
}

// ---------------- output projection: Y @ Wp + bp -> out [B,T,C] f32 ------------
// Round 9 verified (out of top-5): 512 blocks x 64x128 tiles, 2 blocks/CU.
__global__ __launch_bounds__(256) void proj_gemm(const __bf16* __restrict__ Yw,
                                                 const __bf16* __restrict__ WT,
                                                 const float* __restrict__ bias,
                                                 float* __restrict__ out) {
    __shared__ __attribute__((aligned(16))) __bf16 As[2048];
    __shared__ __attribute__((aligned(16))) __bf16 Bs[4096];
    const int o = blockIdx.x;
    const int g = o & 7, r = o >> 3;
    const int m0 = (g * 8 + (r & 7)) * 64;
    const int n0 = (r >> 3) * 128;
    f32x4 acc[2][4];
    const f32x4 zz = {0.f, 0.f, 0.f, 0.f};
#pragma unroll
    for (int i = 0; i < 2; i++)
#pragma unroll
        for (int j = 0; j < 4; j++) acc[i][j] = zz;
    mainloop64(Yw + (size_t)m0 * 1024, WT + (size_t)n0 * 1024, 1024, As, Bs, acc);

    const int lane = threadIdx.x & 63, wid = threadIdx.x >> 6;
    const int quad = lane >> 4, l16 = lane & 15, wm = wid >> 1, wn = wid & 1;
#pragma unroll
    for (int nt = 0; nt < 4; nt++) {
        int col = n0 + wn * 64 + nt * 16 + l16;
        float bv = bias[col];
#pragma unroll
        for (int mt = 0; mt < 2; mt++) {
#pragma unroll
            for (int r4 = 0; r4 < 4; r4++) {
                int m = m0 + wm * 32 + mt * 16 + quad * 4 + r4;
                out[(size_t)m * 1024 + col] = acc[mt][nt][r4] + bv;
            }
        }
    }
}

// ---------------- flash attention v8: 8 waves x 16 q-rows (round-5, verbatim) ---
__global__ __launch_bounds__(512, 1) void attn_kernel(const __bf16* __restrict__ Qg,
                                                      const __bf16* __restrict__ Kg,
                                                      const __bf16* __restrict__ Vtg,
                                                      __bf16* __restrict__ Y) {
    __shared__ __attribute__((aligned(16))) __bf16 Kb[2][128 * 64];  // [key][d] swz
    __shared__ __attribute__((aligned(16))) __bf16 Vb[2][64 * 128];  // [d][key] swz
    __shared__ __attribute__((aligned(16))) __bf16 Ps[8][16 * 136];  // per-wave P
    __shared__ __attribute__((aligned(16))) float  Lw[8][16];        // per-wave l

    const int tid  = threadIdx.x;
    const int lane = tid & 63;
    const int wid  = tid >> 6;          // 0..7
    const int quad = lane >> 4;
    const int l16  = lane & 15;
    const int bkid = blockIdx.x;
    const int head  = ((bkid & 7) << 2) + ((bkid >> 3) & 3);  // 4 heads per XCD
    const int ipair = bkid >> 5;                              // 0..7
    const size_t hbase = (size_t)head * (2048 * 64);
    const f32x4 zz = {0.f, 0.f, 0.f, 0.f};

    const int kr  = lane >> 3;            // K row-in-chunk (= row&7)
    const int kc8 = (lane & 7) ^ kr;      // K swizzled 16B slot
    const int vr  = lane >> 4;            // V row-in-chunk
    const int vl  = lane & 15;

#pragma unroll 1
    for (int itm = 0; itm < 2; itm++) {
        const int qi  = itm ? (15 - ipair) : ipair;  // q-tile index == last key tile
        const int ktl = qi;
        const int q0  = qi << 7;
        const int q0w = q0 + wid * 16;               // this wave's 16 q rows

        bf16x8 qf[2];
#pragma unroll
        for (int kk = 0; kk < 2; kk++)
            qf[kk] = *(const bf16x8*)(Qg + hbase +
                                      (size_t)(q0w + l16) * 64 + kk * 32 + quad * 8);

        f32x4 acc_o[4];
#pragma unroll
        for (int jj = 0; jj < 4; jj++) acc_o[jj] = zz;
        float l_s = 0.f;

        auto stage = [&](int bf, int key0) {
#pragma unroll
            for (int i = 0; i < 2; i++) {
                const int c = wid * 2 + i;
                ld16((char*)&Kb[bf][0] + c * 1024 + lane * 16,
                     Kg + hbase + (size_t)(key0 + c * 8 + kr) * 64 + kc8 * 8);
            }
#pragma unroll
            for (int i = 0; i < 2; i++) {
                const int c = wid * 2 + i;
                const int row = c * 4 + vr;
                const int vc  = vl ^ (row & 7);
                ld16((char*)&Vb[bf][0] + c * 1024 + lane * 16,
                     Vtg + hbase + (size_t)row * 2048 + key0 + vc * 8);
            }
        };

        stage(0, 0);
        __syncthreads();
        int buf = 0;

#pragma unroll 1
        for (int kt = 0; kt <= ktl; kt++) {
            if (kt < ktl) stage(buf ^ 1, (kt + 1) << 7);

            f32x4 accs[8];
#pragma unroll
            for (int mt = 0; mt < 8; mt++) accs[mt] = zz;
#pragma unroll
            for (int kk = 0; kk < 2; kk++) {
#pragma unroll
                for (int mt = 0; mt < 8; mt++) {
                    bf16x8 kf = *(const bf16x8*)(&Kb[buf][(mt * 16 + l16) * 64 +
                                                 (((kk * 4 + quad) ^ (l16 & 7)) << 3)]);
                    accs[mt] = MFMA16(kf, qf[kk], accs[mt]);
                }
            }

            if (kt == ktl) {
#pragma unroll
                for (int mt = 0; mt < 8; mt++) {
                    int q_g = wid * 16 + l16;
#pragma unroll
                    for (int r4 = 0; r4 < 4; r4++) {
                        int key_g = mt * 16 + quad * 4 + r4;
                        if (key_g > q_g) accs[mt][r4] = -1e30f;
                    }
                }
            }

            float s_s = 0.f;
#pragma unroll
            for (int mt = 0; mt < 8; mt++) {
                f32x4 pv;
                pv.x = EXP2(accs[mt].x);
                pv.y = EXP2(accs[mt].y);
                pv.z = EXP2(accs[mt].z);
                pv.w = EXP2(accs[mt].w);
                s_s += (pv.x + pv.y) + (pv.z + pv.w);
                bf16x4 pk;
                pk.x = (__bf16)pv.x; pk.y = (__bf16)pv.y;
                pk.z = (__bf16)pv.z; pk.w = (__bf16)pv.w;
                *(bf16x4*)(&Ps[wid][l16 * 136 + mt * 16 + quad * 4]) = pk;
            }
            {
                float t = s_s;
                t += __shfl_xor(t, 16);
                t += __shfl_xor(t, 32);
                l_s += t;
            }

#pragma unroll
            for (int kk = 0; kk < 4; kk++) {
                bf16x8 pf, vf[4];
                pf = *(const bf16x8*)(&Ps[wid][l16 * 136 + kk * 32 + quad * 8]);
#pragma unroll
                for (int nv = 0; nv < 4; nv++)
                    vf[nv] = *(const bf16x8*)(&Vb[buf][(nv * 16 + l16) * 128 +
                                              (((kk * 4 + quad) ^ (l16 & 7)) << 3)]);
#pragma unroll
                for (int nv = 0; nv < 4; nv++)
                    acc_o[nv] = MFMA16(pf, vf[nv], acc_o[nv]);
            }

            __syncthreads();
            buf ^= 1;
        }

        if (quad == 0) Lw[wid][l16] = l_s;
        float* Om = (float*)&Ps[wid][0];
#pragma unroll
        for (int nv = 0; nv < 4; nv++)
#pragma unroll
            for (int r4 = 0; r4 < 4; r4++)
                Om[(quad * 4 + r4) * 68 + nv * 16 + l16] = acc_o[nv][r4];
        __syncthreads();

        {
            const int q  = lane >> 2;          // 0..15
            const int d0 = (lane & 3) * 16;    // 0,16,32,48
            float li = 1.0f / Lw[wid][q];
            f32x4 s0 = *(const f32x4*)(&Om[q * 68 + d0]);
            f32x4 s1 = *(const f32x4*)(&Om[q * 68 + d0 + 4]);
            f32x4 s2 = *(const f32x4*)(&Om[q * 68 + d0 + 8]);
            f32x4 s3 = *(const f32x4*)(&Om[q * 68 + d0 + 12]);
            bf16x8 o0, o1;
            o0[0] = (__bf16)(s0.x * li); o0[1] = (__bf16)(s0.y * li);
            o0[2] = (__bf16)(s0.z * li); o0[3] = (__bf16)(s0.w * li);
            o0[4] = (__bf16)(s1.x * li); o0[5] = (__bf16)(s1.y * li);
            o0[6] = (__bf16)(s1.z * li); o0[7] = (__bf16)(s1.w * li);
            o1[0] = (__bf16)(s2.x * li); o1[1] = (__bf16)(s2.y * li);
            o1[2] = (__bf16)(s2.z * li); o1[3] = (__bf16)(s2.w * li);
            o1[4] = (__bf16)(s3.x * li); o1[5] = (__bf16)(s3.y * li);
            o1[6] = (__bf16)(s3.z * li); o1[7] = (__bf16)(s3.w * li);
            const int bb = head >> 4, hh = head & 15;
            __bf16* yp = Y + ((size_t)(bb * 2048 + q0w + q)) * 1024 + hh * 64 + d0;
            *(bf16x8*)(yp)     = o0;
            *(bf16x8*)(yp + 8) = o1;
        }
        __syncthreads();
    }
}

// ws layout (bf16 elems), 40 MB total:
// [0,4Mi)     x as bf16 (dead after qkv) -> reused as Y [B,T,C]
// [4Mi,8Mi)   W^T x4 (Wq,Wk,Wv,Wp)
// [8Mi,12Mi)  Q [B,H,T,HD] (pre-scaled)
// [12Mi,16Mi) K [B,H,T,HD]
// [16Mi,20Mi) V^T [B,H,HD,T]  (written directly by qkv_gemm z=2)
#define XB_OFF  0
#define WT_OFF  4194304
#define Q_OFF   8388608
#define K_OFF   12582912
#define VT_OFF  16777216
#define Y_OFF   0

extern "C" void kernel_launch(void* const* d_in, const int* in_sizes, int n_in,
                              void* d_out, int out_size, void* d_ws, size_t ws_size,
                              hipStream_t stream) {
    const float* x  = (const float*)d_in[0];
    const float* Wq = (const float*)d_in[1];
    const float* bq = (const float*)d_in[2];
    const float* Wk = (const float*)d_in[3];
    const float* bk = (const float*)d_in[4];
    const float* Wv = (const float*)d_in[5];
    const float* bv = (const float*)d_in[6];
    const float* Wp = (const float*)d_in[7];
    const float* bp = (const float*)d_in[8];
    __bf16* ws  = (__bf16*)d_ws;
    float*  out = (float*)d_out;
    if (ws_size < (size_t)41943040) return;  // need 40 MB scratch

    prep_kernel<<<dim3(32, 32, 5), dim3(32, 32), 0, stream>>>(x, Wq, Wk, Wv, Wp,
                                                              ws + WT_OFF, ws + XB_OFF);
    qkv_gemm<<<dim3(768), 256, 0, stream>>>(ws + XB_OFF, ws + WT_OFF, bq, bk, bv,
                                            ws + Q_OFF, ws + VT_OFF);
    attn_kernel<<<dim3(256), 512, 0, stream>>>(ws + Q_OFF, ws + K_OFF, ws + VT_OFF,
                                               ws + Y_OFF);
    proj_gemm<<<dim3(512), 256, 0, stream>>>(ws + Y_OFF, ws + WT_OFF + 3 * 1048576, bp, out);
}

// Round 12
// 175.865 us; speedup vs baseline: 1.0583x; 1.0583x over previous
//
#include <hip/hip_runtime.h>
#include <hip/hip_bf16.h>
#include <stdint.h>

typedef __bf16 bf16x8 __attribute__((ext_vector_type(8)));
typedef __bf16 bf16x4 __attribute__((ext_vector_type(4)));
typedef float  f32x4  __attribute__((ext_vector_type(4)));

#define MFMA16(a, b, c) __builtin_amdgcn_mfma_f32_16x16x32_bf16(a, b, c, 0, 0, 0)

#if __has_builtin(__builtin_amdgcn_exp2f)
#define EXP2(x) __builtin_amdgcn_exp2f(x)
#else
#define EXP2(x) exp2f(x)
#endif

// async 16B global->LDS (dest = wave-uniform base + lane*16)
__device__ __forceinline__ void ld16(void* lds, const void* g) {
    __builtin_amdgcn_global_load_lds(
        (const __attribute__((address_space(1))) void*)(uintptr_t)g,
        (__attribute__((address_space(3))) void*)(uint32_t)(uintptr_t)lds,
        16, 0, 0);
}

// ---------------- fused prep: weight transpose x4 + x f32->bf16 ----------------
__global__ __launch_bounds__(1024) void prep_kernel(const float* __restrict__ x,
                                                    const float* __restrict__ W0,
                                                    const float* __restrict__ W1,
                                                    const float* __restrict__ W2,
                                                    const float* __restrict__ W3,
                                                    __bf16* __restrict__ wdst,
                                                    __bf16* __restrict__ xdst) {
    __shared__ __bf16 t[32][33];
    const int z = blockIdx.z;
    const int tx = threadIdx.x, ty = threadIdx.y;
    if (z == 4) {
        int blin = blockIdx.y * 32 + blockIdx.x;
        int i = (blin * 1024 + ty * 32 + tx) * 4;
        float4 v = *(const float4*)(x + i);
        xdst[i]     = (__bf16)v.x;
        xdst[i + 1] = (__bf16)v.y;
        xdst[i + 2] = (__bf16)v.z;
        xdst[i + 3] = (__bf16)v.w;
        return;
    }
    const float* W = (z == 0) ? W0 : (z == 1) ? W1 : (z == 2) ? W2 : W3;
    __bf16* D = wdst + (size_t)z * 1048576;
    t[ty][tx] = (__bf16)W[(size_t)(blockIdx.y * 32 + ty) * 1024 + blockIdx.x * 32 + tx];
    __syncthreads();
    D[(size_t)(blockIdx.x * 32 + ty) * 1024 + blockIdx.y * 32 + tx] = t[tx][ty];
}

// ---------------- shared GEMM mainloop: C[128x128] += A[128xK] * BT[128xK]^T ----
// Round 11 (resubmit, r11 bench was an infra failure): PREFETCH-DBUF schedule
// (attn's proven loop shape, T3-minimal): prologue-stage(0); loop { stage(next
// buf) ; ds_read+MFMA(cur) ; barrier }. One barrier per k-step; the vmcnt(0)
// the compiler inserts before that barrier now waits on loads that had the
// whole MFMA phase to land, instead of r5's stage->barrier draining the full
// staging latency serially 32x. Source addresses LINEAR (r5 form) -- r7/r10
// proved permuted gload_lds sources cost more than the LDS conflicts they fix.
// LDS 32 KB (2 x 16), 3 blocks/CU x 32 = 96 KB <= 160: no residency loss.
// Buffer hazards: iter k's stage(buf^1) overwrites a buffer last read in
// iter k-1, fenced by that iteration's barrier. Numerics identical to r5.
__device__ __forceinline__ void gemm_mainloop(const __bf16* __restrict__ A,
                                              const __bf16* __restrict__ BT,
                                              int K, __bf16* As, __bf16* Bs,
                                              f32x4 acc[4][4]) {
    const int tid  = threadIdx.x;
    const int lane = tid & 63;
    const int wid  = tid >> 6;
    const int quad = lane >> 4;
    const int l16  = lane & 15;
    const int wm   = wid >> 1;
    const int wn   = wid & 1;

    const int srow = wid * 16 + (lane >> 2);
    const int scol = (lane & 3) * 8;
    const int sdst = wid * 512 + lane * 8;

    auto stage = [&](int b, int k0) {
        ld16(As + b * 4096 + sdst,        A  + (size_t)srow        * K + k0 + scol);
        ld16(As + b * 4096 + 2048 + sdst, A  + (size_t)(srow + 64) * K + k0 + scol);
        ld16(Bs + b * 4096 + sdst,        BT + (size_t)srow        * K + k0 + scol);
        ld16(Bs + b * 4096 + 2048 + sdst, BT + (size_t)(srow + 64) * K + k0 + scol);
    };

    stage(0, 0);
    __syncthreads();
    int buf = 0;

    for (int k0 = 0; k0 < K; k0 += 32) {
        if (k0 + 32 < K) stage(buf ^ 1, k0 + 32);   // prefetch next k-step
        bf16x8 af[4], bf[4];
#pragma unroll
        for (int mt = 0; mt < 4; mt++)
            af[mt] = *(const bf16x8*)(As + buf * 4096 +
                                      (wm * 64 + mt * 16 + l16) * 32 + quad * 8);
#pragma unroll
        for (int nt = 0; nt < 4; nt++)
            bf[nt] = *(const bf16x8*)(Bs + buf * 4096 +
                                      (wn * 64 + nt * 16 + l16) * 32 + quad * 8);
#pragma unroll
        for (int mt = 0; mt < 4; mt++)
#pragma unroll
            for (int nt = 0; nt < 4; nt++)
                acc[mt][nt] = MFMA16(af[mt], bf[nt], acc[mt][nt]);
        __syncthreads();   // drains prefetch loads (overlapped with MFMA above)
        buf ^= 1;
    }
}

// ---- proj mainloop: C[64x128] += A[64xK] * BT[128xK]^T, prefetch-dbuf ---------
__device__ __forceinline__ void mainloop64(const __bf16* __restrict__ A,
                                           const __bf16* __restrict__ BT,
                                           int K, __bf16* As, __bf16* Bs,
                                           f32x4 acc[2][4]) {
    const int tid  = threadIdx.x;
    const int lane = tid & 63;
    const int quad = lane >> 4;
    const int l16  = lane & 15;
    const int wid  = tid >> 6;
    const int wm   = wid >> 1;          // 0..1: 32-row half
    const int wn   = wid & 1;           // 0..1: 64-col half
    const int srow = tid >> 2;          // 0..63
    const int scol = (tid & 3) * 8;

    auto stage = [&](int b, int k0) {
        ld16(As + b * 2048 + tid * 8,        A  + (size_t)srow        * K + k0 + scol);
        ld16(Bs + b * 4096 + tid * 8,        BT + (size_t)srow        * K + k0 + scol);
        ld16(Bs + b * 4096 + 2048 + tid * 8, BT + (size_t)(srow + 64) * K + k0 + scol);
    };

    stage(0, 0);
    __syncthreads();
    int buf = 0;

    for (int k0 = 0; k0 < K; k0 += 32) {
        if (k0 + 32 < K) stage(buf ^ 1, k0 + 32);
        bf16x8 af[2], bf[4];
#pragma unroll
        for (int mt = 0; mt < 2; mt++)
            af[mt] = *(const bf16x8*)(As + buf * 2048 +
                                      (wm * 32 + mt * 16 + l16) * 32 + quad * 8);
#pragma unroll
        for (int nt = 0; nt < 4; nt++)
            bf[nt] = *(const bf16x8*)(Bs + buf * 4096 +
                                      (wn * 64 + nt * 16 + l16) * 32 + quad * 8);
#pragma unroll
        for (int mt = 0; mt < 2; mt++)
#pragma unroll
            for (int nt = 0; nt < 4; nt++)
                acc[mt][nt] = MFMA16(af[mt], bf[nt], acc[mt][nt]);
        __syncthreads();
        buf ^= 1;
    }
}

// ---------------- QKV projection: X @ W{q,k,v} + b ------------------------------
// XCD super-tiling (round 3, verified: FETCH 68.7 -> 20.5 MB).
// z=0 -> Q [B,H,T,HD] PRE-SCALED by (1/8)*log2(e), z=1 -> K, z=2 -> V^T
__global__ __launch_bounds__(256) void qkv_gemm(const __bf16* __restrict__ X,
                                                const __bf16* __restrict__ WTb,
                                                const float* __restrict__ b0,
                                                const float* __restrict__ b1,
                                                const float* __restrict__ b2,
                                                __bf16* __restrict__ qk,
                                                __bf16* __restrict__ vt) {
    __shared__ __attribute__((aligned(16))) __bf16 As[8192];   // 2 x 4096 dbuf
    __shared__ __attribute__((aligned(16))) __bf16 Bs[8192];   // 2 x 4096 dbuf
    const int o  = blockIdx.x;
    const int g  = o & 7, r = o >> 3;
    const int mB = ((g >> 1) << 3) + (r & 7);     // m-tile 0..31
    const int nz = (g & 1) * 12 + (r >> 3);       // 0..23
    const int z  = nz >> 3;                       // 0..2
    const int n  = nz & 7;                        // 0..7
    const __bf16* BT   = WTb + (size_t)z * 1048576;
    const float* bias  = (z == 0) ? b0 : (z == 1) ? b1 : b2;
    const int m0 = mB * 128, n0 = n * 128;
    f32x4 acc[4][4];
    const f32x4 zz = {0.f, 0.f, 0.f, 0.f};
#pragma unroll
    for (int i = 0; i < 4; i++)
#pragma unroll
        for (int j = 0; j < 4; j++) acc[i][j] = zz;
    gemm_mainloop(X + (size_t)m0 * 1024, BT + (size_t)n0 * 1024, 1024, As, Bs, acc);

    const int lane = threadIdx.x & 63, wid = threadIdx.x >> 6;
    const int quad = lane >> 4, l16 = lane & 15, wm = wid >> 1, wn = wid & 1;
    if (z == 2) {
        // V^T epilogue: vt[((b*16+h)*64+hd)*2048 + t], 4 consecutive t packed
#pragma unroll
        for (int nt = 0; nt < 4; nt++) {
            int col = n0 + wn * 64 + nt * 16 + l16;
            float bv = bias[col];
            int h = col >> 6, hd = col & 63;
#pragma unroll
            for (int mt = 0; mt < 4; mt++) {
                int m = m0 + wm * 64 + mt * 16 + quad * 4;
                int b = m >> 11, tt = m & 2047;
                bf16x4 pk;
                pk.x = (__bf16)(acc[mt][nt].x + bv);
                pk.y = (__bf16)(acc[mt][nt].y + bv);
                pk.z = (__bf16)(acc[mt][nt].z + bv);
                pk.w = (__bf16)(acc[mt][nt].w + bv);
                *(bf16x4*)(vt + ((size_t)((b * 16 + h) * 64 + hd)) * 2048 + tt) = pk;
            }
        }
    } else {
        // softmax scale (1/sqrt(64))*log2(e) folded into Q here (z==0)
        const float sq = (z == 0) ? 0.18033688011112042f : 1.0f;
        __bf16* dst = qk + (size_t)z * 4194304;
#pragma unroll
        for (int nt = 0; nt < 4; nt++) {
            int col = n0 + wn * 64 + nt * 16 + l16;
            float bv = bias[col];
            int h = col >> 6, hd = col & 63;
#pragma unroll
            for (int mt = 0; mt < 4; mt++) {
#pragma unroll
                for (int r4 = 0; r4 < 4; r4++) {
                    int m = m0 + wm * 64 + mt * 16 + quad * 4 + r4;
                    int b = m >> 11, tt = m & 2047;
                    float v = (acc[mt][nt][r4] + bv) * sq;
                    dst[((size_t)((b * 16 + h) * 2048 + tt)) * 64 + hd] = (__bf16)v;
                }
            }
        }
    }
}

// ---------------- output projection: Y @ Wp + bp -> out [B,T,C] f32 ------------
// Round 9 verified (out of top-5): 512 blocks x 64x128 tiles, 2 blocks/CU.
// Round 11: prefetch-dbuf mainloop (24 KB LDS, 2 blocks/CU -> 48 KB, fine).
__global__ __launch_bounds__(256) void proj_gemm(const __bf16* __restrict__ Yw,
                                                 const __bf16* __restrict__ WT,
                                                 const float* __restrict__ bias,
                                                 float* __restrict__ out) {
    __shared__ __attribute__((aligned(16))) __bf16 As[4096];   // 2 x 2048 dbuf
    __shared__ __attribute__((aligned(16))) __bf16 Bs[8192];   // 2 x 4096 dbuf
    const int o = blockIdx.x;
    const int g = o & 7, r = o >> 3;
    const int m0 = (g * 8 + (r & 7)) * 64;
    const int n0 = (r >> 3) * 128;
    f32x4 acc[2][4];
    const f32x4 zz = {0.f, 0.f, 0.f, 0.f};
#pragma unroll
    for (int i = 0; i < 2; i++)
#pragma unroll
        for (int j = 0; j < 4; j++) acc[i][j] = zz;
    mainloop64(Yw + (size_t)m0 * 1024, WT + (size_t)n0 * 1024, 1024, As, Bs, acc);

    const int lane = threadIdx.x & 63, wid = threadIdx.x >> 6;
    const int quad = lane >> 4, l16 = lane & 15, wm = wid >> 1, wn = wid & 1;
#pragma unroll
    for (int nt = 0; nt < 4; nt++) {
        int col = n0 + wn * 64 + nt * 16 + l16;
        float bv = bias[col];
#pragma unroll
        for (int mt = 0; mt < 2; mt++) {
#pragma unroll
            for (int r4 = 0; r4 < 4; r4++) {
                int m = m0 + wm * 32 + mt * 16 + quad * 4 + r4;
                out[(size_t)m * 1024 + col] = acc[mt][nt][r4] + bv;
            }
        }
    }
}

// ---------------- flash attention v8: 8 waves x 16 q-rows (round-5, verbatim) ---
__global__ __launch_bounds__(512, 1) void attn_kernel(const __bf16* __restrict__ Qg,
                                                      const __bf16* __restrict__ Kg,
                                                      const __bf16* __restrict__ Vtg,
                                                      __bf16* __restrict__ Y) {
    __shared__ __attribute__((aligned(16))) __bf16 Kb[2][128 * 64];  // [key][d] swz
    __shared__ __attribute__((aligned(16))) __bf16 Vb[2][64 * 128];  // [d][key] swz
    __shared__ __attribute__((aligned(16))) __bf16 Ps[8][16 * 136];  // per-wave P
    __shared__ __attribute__((aligned(16))) float  Lw[8][16];        // per-wave l

    const int tid  = threadIdx.x;
    const int lane = tid & 63;
    const int wid  = tid >> 6;          // 0..7
    const int quad = lane >> 4;
    const int l16  = lane & 15;
    const int bkid = blockIdx.x;
    const int head  = ((bkid & 7) << 2) + ((bkid >> 3) & 3);  // 4 heads per XCD
    const int ipair = bkid >> 5;                              // 0..7
    const size_t hbase = (size_t)head * (2048 * 64);
    const f32x4 zz = {0.f, 0.f, 0.f, 0.f};

    const int kr  = lane >> 3;            // K row-in-chunk (= row&7)
    const int kc8 = (lane & 7) ^ kr;      // K swizzled 16B slot
    const int vr  = lane >> 4;            // V row-in-chunk
    const int vl  = lane & 15;

#pragma unroll 1
    for (int itm = 0; itm < 2; itm++) {
        const int qi  = itm ? (15 - ipair) : ipair;  // q-tile index == last key tile
        const int ktl = qi;
        const int q0  = qi << 7;
        const int q0w = q0 + wid * 16;               // this wave's 16 q rows

        bf16x8 qf[2];
#pragma unroll
        for (int kk = 0; kk < 2; kk++)
            qf[kk] = *(const bf16x8*)(Qg + hbase +
                                      (size_t)(q0w + l16) * 64 + kk * 32 + quad * 8);

        f32x4 acc_o[4];
#pragma unroll
        for (int jj = 0; jj < 4; jj++) acc_o[jj] = zz;
        float l_s = 0.f;

        auto stage = [&](int bf, int key0) {
#pragma unroll
            for (int i = 0; i < 2; i++) {
                const int c = wid * 2 + i;
                ld16((char*)&Kb[bf][0] + c * 1024 + lane * 16,
                     Kg + hbase + (size_t)(key0 + c * 8 + kr) * 64 + kc8 * 8);
            }
#pragma unroll
            for (int i = 0; i < 2; i++) {
                const int c = wid * 2 + i;
                const int row = c * 4 + vr;
                const int vc  = vl ^ (row & 7);
                ld16((char*)&Vb[bf][0] + c * 1024 + lane * 16,
                     Vtg + hbase + (size_t)row * 2048 + key0 + vc * 8);
            }
        };

        stage(0, 0);
        __syncthreads();
        int buf = 0;

#pragma unroll 1
        for (int kt = 0; kt <= ktl; kt++) {
            if (kt < ktl) stage(buf ^ 1, (kt + 1) << 7);

            f32x4 accs[8];
#pragma unroll
            for (int mt = 0; mt < 8; mt++) accs[mt] = zz;
#pragma unroll
            for (int kk = 0; kk < 2; kk++) {
#pragma unroll
                for (int mt = 0; mt < 8; mt++) {
                    bf16x8 kf = *(const bf16x8*)(&Kb[buf][(mt * 16 + l16) * 64 +
                                                 (((kk * 4 + quad) ^ (l16 & 7)) << 3)]);
                    accs[mt] = MFMA16(kf, qf[kk], accs[mt]);
                }
            }

            if (kt == ktl) {
#pragma unroll
                for (int mt = 0; mt < 8; mt++) {
                    int q_g = wid * 16 + l16;
#pragma unroll
                    for (int r4 = 0; r4 < 4; r4++) {
                        int key_g = mt * 16 + quad * 4 + r4;
                        if (key_g > q_g) accs[mt][r4] = -1e30f;
                    }
                }
            }

            float s_s = 0.f;
#pragma unroll
            for (int mt = 0; mt < 8; mt++) {
                f32x4 pv;
                pv.x = EXP2(accs[mt].x);
                pv.y = EXP2(accs[mt].y);
                pv.z = EXP2(accs[mt].z);
                pv.w = EXP2(accs[mt].w);
                s_s += (pv.x + pv.y) + (pv.z + pv.w);
                bf16x4 pk;
                pk.x = (__bf16)pv.x; pk.y = (__bf16)pv.y;
                pk.z = (__bf16)pv.z; pk.w = (__bf16)pv.w;
                *(bf16x4*)(&Ps[wid][l16 * 136 + mt * 16 + quad * 4]) = pk;
            }
            {
                float t = s_s;
                t += __shfl_xor(t, 16);
                t += __shfl_xor(t, 32);
                l_s += t;
            }

#pragma unroll
            for (int kk = 0; kk < 4; kk++) {
                bf16x8 pf, vf[4];
                pf = *(const bf16x8*)(&Ps[wid][l16 * 136 + kk * 32 + quad * 8]);
#pragma unroll
                for (int nv = 0; nv < 4; nv++)
                    vf[nv] = *(const bf16x8*)(&Vb[buf][(nv * 16 + l16) * 128 +
                                              (((kk * 4 + quad) ^ (l16 & 7)) << 3)]);
#pragma unroll
                for (int nv = 0; nv < 4; nv++)
                    acc_o[nv] = MFMA16(pf, vf[nv], acc_o[nv]);
            }

            __syncthreads();
            buf ^= 1;
        }

        if (quad == 0) Lw[wid][l16] = l_s;
        float* Om = (float*)&Ps[wid][0];
#pragma unroll
        for (int nv = 0; nv < 4; nv++)
#pragma unroll
            for (int r4 = 0; r4 < 4; r4++)
                Om[(quad * 4 + r4) * 68 + nv * 16 + l16] = acc_o[nv][r4];
        __syncthreads();

        {
            const int q  = lane >> 2;          // 0..15
            const int d0 = (lane & 3) * 16;    // 0,16,32,48
            float li = 1.0f / Lw[wid][q];
            f32x4 s0 = *(const f32x4*)(&Om[q * 68 + d0]);
            f32x4 s1 = *(const f32x4*)(&Om[q * 68 + d0 + 4]);
            f32x4 s2 = *(const f32x4*)(&Om[q * 68 + d0 + 8]);
            f32x4 s3 = *(const f32x4*)(&Om[q * 68 + d0 + 12]);
            bf16x8 o0, o1;
            o0[0] = (__bf16)(s0.x * li); o0[1] = (__bf16)(s0.y * li);
            o0[2] = (__bf16)(s0.z * li); o0[3] = (__bf16)(s0.w * li);
            o0[4] = (__bf16)(s1.x * li); o0[5] = (__bf16)(s1.y * li);
            o0[6] = (__bf16)(s1.z * li); o0[7] = (__bf16)(s1.w * li);
            o1[0] = (__bf16)(s2.x * li); o1[1] = (__bf16)(s2.y * li);
            o1[2] = (__bf16)(s2.z * li); o1[3] = (__bf16)(s2.w * li);
            o1[4] = (__bf16)(s3.x * li); o1[5] = (__bf16)(s3.y * li);
            o1[6] = (__bf16)(s3.z * li); o1[7] = (__bf16)(s3.w * li);
            const int bb = head >> 4, hh = head & 15;
            __bf16* yp = Y + ((size_t)(bb * 2048 + q0w + q)) * 1024 + hh * 64 + d0;
            *(bf16x8*)(yp)     = o0;
            *(bf16x8*)(yp + 8) = o1;
        }
        __syncthreads();
    }
}

// ws layout (bf16 elems), 40 MB total:
// [0,4Mi)     x as bf16 (dead after qkv) -> reused as Y [B,T,C]
// [4Mi,8Mi)   W^T x4 (Wq,Wk,Wv,Wp)
// [8Mi,12Mi)  Q [B,H,T,HD] (pre-scaled)
// [12Mi,16Mi) K [B,H,T,HD]
// [16Mi,20Mi) V^T [B,H,HD,T]  (written directly by qkv_gemm z=2)
#define XB_OFF  0
#define WT_OFF  4194304
#define Q_OFF   8388608
#define K_OFF   12582912
#define VT_OFF  16777216
#define Y_OFF   0

extern "C" void kernel_launch(void* const* d_in, const int* in_sizes, int n_in,
                              void* d_out, int out_size, void* d_ws, size_t ws_size,
                              hipStream_t stream) {
    const float* x  = (const float*)d_in[0];
    const float* Wq = (const float*)d_in[1];
    const float* bq = (const float*)d_in[2];
    const float* Wk = (const float*)d_in[3];
    const float* bk = (const float*)d_in[4];
    const float* Wv = (const float*)d_in[5];
    const float* bv = (const float*)d_in[6];
    const float* Wp = (const float*)d_in[7];
    const float* bp = (const float*)d_in[8];
    __bf16* ws  = (__bf16*)d_ws;
    float*  out = (float*)d_out;
    if (ws_size < (size_t)41943040) return;  // need 40 MB scratch

    prep_kernel<<<dim3(32, 32, 5), dim3(32, 32), 0, stream>>>(x, Wq, Wk, Wv, Wp,
                                                              ws + WT_OFF, ws + XB_OFF);
    qkv_gemm<<<dim3(768), 256, 0, stream>>>(ws + XB_OFF, ws + WT_OFF, bq, bk, bv,
                                            ws + Q_OFF, ws + VT_OFF);
    attn_kernel<<<dim3(256), 512, 0, stream>>>(ws + Q_OFF, ws + K_OFF, ws + VT_OFF,
                                               ws + Y_OFF);
    proj_gemm<<<dim3(512), 256, 0, stream>>>(ws + Y_OFF, ws + WT_OFF + 3 * 1048576, bp, out);
}